// Round 3
// baseline (303.159 us; speedup 1.0000x reference)
//
#include <hip/hip_runtime.h>
#include <math.h>

// SCARF KNN+LBS-blend kernel.
// B=1, N=32768 points, V=10475 template verts, K=6, J=55.
// out = [ xyz_dist (N floats) | xyz_transform (N*16 floats) ]
//
// NUMERICS: the checker's reference replicates the jax ops in f32 ("ref=np").
// With random lbs rows, conf gates every k>0 to zero, so the transform output
// is the raw argmin's 4x4 — one rank-0 flip costs absmax ~3.5. We therefore
// replicate the reference's f32 rounding exactly:
//   p2 = (px^2 + py^2) + pz^2            (multiply + sequential reduce, no fma)
//   t2 = (tx^2 + ty^2) + tz^2            (same)
//   cross = fma(pz,tz, fma(py,ty, px*tx))  (sgemm-style ascending-k fma chain)
//   d2 = max((p2 + t2) - 2*cross, 0)     (separate elementwise ops)
// Contraction is disabled so the compiler can't restructure these.
#pragma clang fp contract(off)

#define NPTS  32768
#define NV    10475
#define JW    55
#define TILE  2048        // template verts staged in LDS per tile (32 KB as float4)
#define PPB   64          // points per block
#define SPLIT 4           // threads cooperating per point
#define BLOCK (PPB * SPLIT)

// strict-< insertion keeps per-thread scan-order (== index-order) stability on ties
#define INS(dd, vv) \
  if ((dd) < kd5) { \
    if ((dd) < kd4) { kd5 = kd4; ki5 = ki4; \
      if ((dd) < kd3) { kd4 = kd3; ki4 = ki3; \
        if ((dd) < kd2) { kd3 = kd2; ki3 = ki2; \
          if ((dd) < kd1) { kd2 = kd1; ki2 = ki1; \
            if ((dd) < kd0) { kd1 = kd0; ki1 = ki0; kd0 = (dd); ki0 = (vv); } \
            else            { kd1 = (dd); ki1 = (vv); } \
          } else { kd2 = (dd); ki2 = (vv); } \
        } else { kd3 = (dd); ki3 = (vv); } \
      } else { kd4 = (dd); ki4 = (vv); } \
    } else { kd5 = (dd); ki5 = (vv); } \
  }

// lexicographic (dist, idx) compare for the cross-thread merge (matches jax top_k tie rule)
#define LTL(dd, vv, D, I) ((dd) < (D) || ((dd) == (D) && (vv) < (I)))

#define INSL(dd, vv) \
  if (LTL(dd, vv, fd5, fi5)) { \
    if (LTL(dd, vv, fd4, fi4)) { fd5 = fd4; fi5 = fi4; \
      if (LTL(dd, vv, fd3, fi3)) { fd4 = fd3; fi4 = fi3; \
        if (LTL(dd, vv, fd2, fi2)) { fd3 = fd2; fi3 = fi2; \
          if (LTL(dd, vv, fd1, fi1)) { fd2 = fd1; fi2 = fi1; \
            if (LTL(dd, vv, fd0, fi0)) { fd1 = fd0; fi1 = fi0; fd0 = (dd); fi0 = (vv); } \
            else                       { fd1 = (dd); fi1 = (vv); } \
          } else { fd2 = (dd); fi2 = (vv); } \
        } else { fd3 = (dd); fi3 = (vv); } \
      } else { fd4 = (dd); fi4 = (vv); } \
    } else { fd5 = (dd); fi5 = (vv); } \
  }

#define ACCUM(NK, FIK) { \
    const float4 t = *(const float4*)(vtf + (long)(FIK) * 16 + g * 4); \
    acc.x = fmaf((NK), t.x, acc.x); acc.y = fmaf((NK), t.y, acc.y); \
    acc.z = fmaf((NK), t.z, acc.z); acc.w = fmaf((NK), t.w, acc.w); }

__global__ __launch_bounds__(BLOCK, 2)
void scarf_knn_lbs(const float* __restrict__ lbs,   // [NV][JW]
                   const float* __restrict__ vtf,   // [NV][16]
                   const float* __restrict__ pts,   // [NPTS][3]
                   const float* __restrict__ tpl,   // [NV][3]
                   float* __restrict__ out_dist,    // [NPTS]
                   float* __restrict__ out_tf)      // [NPTS][16]
{
    __shared__ float4 s_t[TILE];

    const int tid = threadIdx.x;
    const int g   = tid & (SPLIT - 1);
    const int p   = blockIdx.x * PPB + (tid >> 2);

    const float px = pts[p * 3 + 0];
    const float py = pts[p * 3 + 1];
    const float pz = pts[p * 3 + 2];
    // p2 replicating jnp.sum(points*points, -1): ((x^2 + y^2) + z^2), no fma
    const float p2 = (px * px + py * py) + pz * pz;

    // per-thread register top-6 (static access only — keep out of scratch)
    float kd0 = 3.4e38f, kd1 = 3.4e38f, kd2 = 3.4e38f, kd3 = 3.4e38f, kd4 = 3.4e38f, kd5 = 3.4e38f;
    int   ki0 = -1, ki1 = -1, ki2 = -1, ki3 = -1, ki4 = -1, ki5 = -1;

    for (int base = 0; base < NV; base += TILE) {
        const int tn = (NV - base < TILE) ? (NV - base) : TILE;
        __syncthreads();
        for (int i = tid; i < tn; i += BLOCK) {
            const float x = tpl[(base + i) * 3 + 0];
            const float y = tpl[(base + i) * 3 + 1];
            const float z = tpl[(base + i) * 3 + 2];
            // t2 replicating jnp.sum(t*t, -1): ((x^2 + y^2) + z^2), no fma
            const float t2 = (x * x + y * y) + z * z;
            s_t[i] = make_float4(x, y, z, t2);
        }
        __syncthreads();
        #pragma unroll 4
        for (int i = g; i < tn; i += SPLIT) {
            const float4 t = s_t[i];
            // cross replicating sgemm ascending-k fma accumulation:
            // acc = fma(pz,tz, fma(py,ty, px*tx))
            const float cross = fmaf(pz, t.z, fmaf(py, t.y, px * t.x));
            // d2 = max((p2 + t2) - 2*cross, 0) — separate elementwise ops
            const float a  = p2 + t.w;
            const float b  = 2.0f * cross;
            const float dd = fmaxf(a - b, 0.0f);
            const int   vv = base + i;
            INS(dd, vv);
        }
    }

    // merge the 4 per-thread lists (all 4 lanes replicate the merge -> identical result)
    float fd0 = 3.4e38f, fd1 = 3.4e38f, fd2 = 3.4e38f, fd3 = 3.4e38f, fd4 = 3.4e38f, fd5 = 3.4e38f;
    int   fi0 = -1, fi1 = -1, fi2 = -1, fi3 = -1, fi4 = -1, fi5 = -1;
    const int blane = (tid & 63) & ~(SPLIT - 1);
    #pragma unroll
    for (int s = 0; s < SPLIT; ++s) {
        float dd; int vv;
        dd = __shfl(kd0, blane + s); vv = __shfl(ki0, blane + s); INSL(dd, vv);
        dd = __shfl(kd1, blane + s); vv = __shfl(ki1, blane + s); INSL(dd, vv);
        dd = __shfl(kd2, blane + s); vv = __shfl(ki2, blane + s); INSL(dd, vv);
        dd = __shfl(kd3, blane + s); vv = __shfl(ki3, blane + s); INSL(dd, vv);
        dd = __shfl(kd4, blane + s); vv = __shfl(ki4, blane + s); INSL(dd, vv);
        dd = __shfl(kd5, blane + s); vv = __shfl(ki5, blane + s); INSL(dd, vv);
    }

    // ---- phase 2: confidence gating ----
    // thread g computes conf for neighbor k=g+1; thread 0 additionally k=5. k=0 conf==1 always.
    const float* a0 = lbs + (long)fi0 * JW;
    const int vik = (g == 0) ? fi1 : (g == 1) ? fi2 : (g == 2) ? fi3 : fi4;
    const float* bk = lbs + (long)vik * JW;
    float sk = 0.0f;
    for (int j = 0; j < JW; ++j) sk += fabsf(bk[j] - a0[j]);
    int m = (expf(-sk / 0.02f) > 0.9f) ? (2 << g) : 0;
    if (g == 0) {
        const float* b5 = lbs + (long)fi5 * JW;
        float s5 = 0.0f;
        for (int j = 0; j < JW; ++j) s5 += fabsf(b5[j] - a0[j]);
        if (expf(-s5 / 0.02f) > 0.9f) m |= 32;
    }
    m |= __shfl_xor(m, 1);
    m |= __shfl_xor(m, 2);

    const float w0 = expf(-fd0);
    const float w1 = (m & 2)  ? expf(-fd1) : 0.0f;
    const float w2 = (m & 4)  ? expf(-fd2) : 0.0f;
    const float w3 = (m & 8)  ? expf(-fd3) : 0.0f;
    const float w4 = (m & 16) ? expf(-fd4) : 0.0f;
    const float w5 = (m & 32) ? expf(-fd5) : 0.0f;
    const float inv = 1.0f / (w0 + w1 + w2 + w3 + w4 + w5);
    const float n0 = w0 * inv, n1 = w1 * inv, n2 = w2 * inv;
    const float n3 = w3 * inv, n4 = w4 * inv, n5 = w5 * inv;

    if (g == 0) {
        out_dist[p] = n0 * fd0 + n1 * fd1 + n2 * fd2 + n3 * fd3 + n4 * fd4 + n5 * fd5;
    }

    float4 acc = make_float4(0.0f, 0.0f, 0.0f, 0.0f);
    ACCUM(n0, fi0); ACCUM(n1, fi1); ACCUM(n2, fi2);
    ACCUM(n3, fi3); ACCUM(n4, fi4); ACCUM(n5, fi5);
    *(float4*)(out_tf + (long)p * 16 + g * 4) = acc;
}

extern "C" void kernel_launch(void* const* d_in, const int* in_sizes, int n_in,
                              void* d_out, int out_size, void* d_ws, size_t ws_size,
                              hipStream_t stream) {
    const float* lbs = (const float*)d_in[0];   // [10475][55]
    const float* vtf = (const float*)d_in[1];   // [10475][4][4]
    const float* pts = (const float*)d_in[2];   // [32768][3]
    const float* tpl = (const float*)d_in[3];   // [10475][3]
    float* out = (float*)d_out;
    scarf_knn_lbs<<<NPTS / PPB, BLOCK, 0, stream>>>(lbs, vtf, pts, tpl, out, out + NPTS);
}

// Round 4
// 263.509 us; speedup vs baseline: 1.1505x; 1.1505x over previous
//
#include <hip/hip_runtime.h>
#include <math.h>

// SCARF KNN+LBS-blend kernel.  B=1, N=32768, V=10475, K=6, J=55.
// out = [ xyz_dist (N floats) | xyz_transform (N*16 floats) ]
//
// NUMERICS (verified passing in round 3): replicate the np reference's f32
// rounding exactly for the KNN ordering:
//   p2 = (px^2 + py^2) + pz^2            (no fma)
//   t2 = (tx^2 + ty^2) + tz^2            (no fma)
//   cross = fma(pz,tz, fma(py,ty, px*tx))  (ascending-k fma chain)
//   d2 = max((p2 + t2) - 2*cross, 0)
// We store DOUBLED template coords (2tx,2ty,2tz) in LDS: the fma chain on
// doubled coords yields exactly 2*cross (powers of 2 commute with rounding),
// bit-identical to round 3's (p2+t2) - 2*cross. Contraction off globally.
#pragma clang fp contract(off)

#define NPTS  32768
#define NV    10475
#define JW    55
#define TILE  2048        // float4 -> 32 KB LDS
#define SPLIT 16          // lanes cooperating per point
#define BLOCK 256
#define PPB   32          // points per block = BLOCK/SPLIT*2  -> grid 1024

// strict-< sorted insert (ascending scan order => first-index-wins on ties)
#define INS6(dd, vv, D0,I0,D1,I1,D2,I2,D3,I3,D4,I4,D5,I5) \
  if ((dd) < D5) { \
    if ((dd) < D4) { D5=D4; I5=I4; \
      if ((dd) < D3) { D4=D3; I4=I3; \
        if ((dd) < D2) { D3=D2; I3=I2; \
          if ((dd) < D1) { D2=D1; I2=I1; \
            if ((dd) < D0) { D1=D0; I1=I0; D0=(dd); I0=(vv); } \
            else { D1=(dd); I1=(vv); } \
          } else { D2=(dd); I2=(vv); } \
        } else { D3=(dd); I3=(vv); } \
      } else { D4=(dd); I4=(vv); } \
    } else { D5=(dd); I5=(vv); } \
  }

// lexicographic (dist, idx) insert for cross-lane merge (jax top_k tie rule)
#define LTL(dd, vv, D, I) ((dd) < (D) || ((dd) == (D) && (vv) < (I)))
#define INSL6(dd, vv, D0,I0,D1,I1,D2,I2,D3,I3,D4,I4,D5,I5) \
  if (LTL(dd, vv, D5, I5)) { \
    if (LTL(dd, vv, D4, I4)) { D5=D4; I5=I4; \
      if (LTL(dd, vv, D3, I3)) { D4=D3; I4=I3; \
        if (LTL(dd, vv, D2, I2)) { D3=D2; I3=I2; \
          if (LTL(dd, vv, D1, I1)) { D2=D1; I2=I1; \
            if (LTL(dd, vv, D0, I0)) { D1=D0; I1=I0; D0=(dd); I0=(vv); } \
            else { D1=(dd); I1=(vv); } \
          } else { D2=(dd); I2=(vv); } \
        } else { D3=(dd); I3=(vv); } \
      } else { D4=(dd); I4=(vv); } \
    } else { D5=(dd); I5=(vv); } \
  }

// butterfly step: snapshot partner's 6 FIRST (partner mutates in lockstep), then insert
#define MERGE6(S, D0,I0,D1,I1,D2,I2,D3,I3,D4,I4,D5,I5) { \
    float m0=__shfl_xor(D0,S), m1=__shfl_xor(D1,S), m2=__shfl_xor(D2,S), \
          m3=__shfl_xor(D3,S), m4=__shfl_xor(D4,S), m5=__shfl_xor(D5,S); \
    int   j0=__shfl_xor(I0,S), j1=__shfl_xor(I1,S), j2=__shfl_xor(I2,S), \
          j3=__shfl_xor(I3,S), j4=__shfl_xor(I4,S), j5=__shfl_xor(I5,S); \
    INSL6(m0,j0, D0,I0,D1,I1,D2,I2,D3,I3,D4,I4,D5,I5); \
    INSL6(m1,j1, D0,I0,D1,I1,D2,I2,D3,I3,D4,I4,D5,I5); \
    INSL6(m2,j2, D0,I0,D1,I1,D2,I2,D3,I3,D4,I4,D5,I5); \
    INSL6(m3,j3, D0,I0,D1,I1,D2,I2,D3,I3,D4,I4,D5,I5); \
    INSL6(m4,j4, D0,I0,D1,I1,D2,I2,D3,I3,D4,I4,D5,I5); \
    INSL6(m5,j5, D0,I0,D1,I1,D2,I2,D3,I3,D4,I4,D5,I5); }

#define ALL6(M) M(0) M(1) M(2) M(3) M(4) M(5)

__global__ __launch_bounds__(BLOCK, 4)
void scarf_knn_lbs(const float* __restrict__ lbs,   // [NV][JW]
                   const float* __restrict__ vtf,   // [NV][16]
                   const float* __restrict__ pts,   // [NPTS][3]
                   const float* __restrict__ tpl,   // [NV][3]
                   float* __restrict__ out_dist,    // [NPTS]
                   float* __restrict__ out_tf)      // [NPTS][16]
{
    __shared__ float4 s_t[TILE];

    const int tid = threadIdx.x;
    const int h   = tid & (SPLIT - 1);       // lane within point-group
    const int grp = tid >> 4;                // 0..15 point-pair group in block
    const int pA  = blockIdx.x * PPB + grp * 2;
    const int pB  = pA + 1;

    const float pxA = pts[pA*3+0], pyA = pts[pA*3+1], pzA = pts[pA*3+2];
    const float pxB = pts[pB*3+0], pyB = pts[pB*3+1], pzB = pts[pB*3+2];
    const float p2A = (pxA*pxA + pyA*pyA) + pzA*pzA;
    const float p2B = (pxB*pxB + pyB*pyB) + pzB*pzB;

    float aD0=3.4e38f,aD1=3.4e38f,aD2=3.4e38f,aD3=3.4e38f,aD4=3.4e38f,aD5=3.4e38f;
    int   aI0=-1,aI1=-1,aI2=-1,aI3=-1,aI4=-1,aI5=-1;
    float bD0=3.4e38f,bD1=3.4e38f,bD2=3.4e38f,bD3=3.4e38f,bD4=3.4e38f,bD5=3.4e38f;
    int   bI0=-1,bI1=-1,bI2=-1,bI3=-1,bI4=-1,bI5=-1;

    for (int base = 0; base < NV; base += TILE) {
        const int tn = (NV - base < TILE) ? (NV - base) : TILE;
        __syncthreads();
        for (int i = tid; i < tn; i += BLOCK) {
            const float x = tpl[(base+i)*3+0];
            const float y = tpl[(base+i)*3+1];
            const float z = tpl[(base+i)*3+2];
            const float t2 = (x*x + y*y) + z*z;      // reference t2 rounding
            s_t[i] = make_float4(x+x, y+y, z+z, t2); // doubled coords (exact)
        }
        __syncthreads();
        #pragma unroll 2
        for (int i = h; i < tn; i += SPLIT) {
            const float4 t = s_t[i];
            const int vv = base + i;
            {
                const float cr = fmaf(pzA, t.z, fmaf(pyA, t.y, pxA * t.x)); // == 2*cross
                const float dd = fmaxf((p2A + t.w) - cr, 0.0f);
                INS6(dd, vv, aD0,aI0,aD1,aI1,aD2,aI2,aD3,aI3,aD4,aI4,aD5,aI5);
            }
            {
                const float cr = fmaf(pzB, t.z, fmaf(pyB, t.y, pxB * t.x));
                const float dd = fmaxf((p2B + t.w) - cr, 0.0f);
                INS6(dd, vv, bD0,bI0,bD1,bI1,bD2,bI2,bD3,bI3,bD4,bI4,bD5,bI5);
            }
        }
    }

    // butterfly merge across the 16-lane group; all lanes end with full top-6
    MERGE6(1, aD0,aI0,aD1,aI1,aD2,aI2,aD3,aI3,aD4,aI4,aD5,aI5);
    MERGE6(2, aD0,aI0,aD1,aI1,aD2,aI2,aD3,aI3,aD4,aI4,aD5,aI5);
    MERGE6(4, aD0,aI0,aD1,aI1,aD2,aI2,aD3,aI3,aD4,aI4,aD5,aI5);
    MERGE6(8, aD0,aI0,aD1,aI1,aD2,aI2,aD3,aI3,aD4,aI4,aD5,aI5);
    MERGE6(1, bD0,bI0,bD1,bI1,bD2,bI2,bD3,bI3,bD4,bI4,bD5,bI5);
    MERGE6(2, bD0,bI0,bD1,bI1,bD2,bI2,bD3,bI3,bD4,bI4,bD5,bI5);
    MERGE6(4, bD0,bI0,bD1,bI1,bD2,bI2,bD3,bI3,bD4,bI4,bD5,bI5);
    MERGE6(8, bD0,bI0,bD1,bI1,bD2,bI2,bD3,bI3,bD4,bI4,bD5,bI5);

    // ---- phase 2: confidence gating ----
    // lanes 0..4: point A neighbors k=1..5 ; lanes 8..12: point B k=1..5
    int rowRef, rowK, bit; bool valid;
    if (h < 8) {
        rowRef = aI0; valid = (h < 5); bit = 2 << h;
        rowK = (h==0)?aI1:(h==1)?aI2:(h==2)?aI3:(h==3)?aI4:(h==4)?aI5:aI0;
    } else {
        rowRef = bI0; valid = (h < 13); bit = 0x200 << (h - 8);
        rowK = (h==8)?bI1:(h==9)?bI2:(h==10)?bI3:(h==11)?bI4:(h==12)?bI5:bI0;
    }
    const float* ra = lbs + (long)rowK  * JW;
    const float* rb = lbs + (long)rowRef * JW;
    float s = 0.0f;
    for (int j = 0; j < JW; ++j) s += fabsf(ra[j] - rb[j]);
    int m = (valid && (expf(-s / 0.02f) > 0.9f)) ? bit : 0;
    m |= __shfl_xor(m, 1); m |= __shfl_xor(m, 2);
    m |= __shfl_xor(m, 4); m |= __shfl_xor(m, 8);

    const float wA0 = expf(-aD0);
    const float wA1 = (m & 0x002) ? expf(-aD1) : 0.0f;
    const float wA2 = (m & 0x004) ? expf(-aD2) : 0.0f;
    const float wA3 = (m & 0x008) ? expf(-aD3) : 0.0f;
    const float wA4 = (m & 0x010) ? expf(-aD4) : 0.0f;
    const float wA5 = (m & 0x020) ? expf(-aD5) : 0.0f;
    const float invA = 1.0f / (wA0+wA1+wA2+wA3+wA4+wA5);
    const float nA0=wA0*invA, nA1=wA1*invA, nA2=wA2*invA,
                nA3=wA3*invA, nA4=wA4*invA, nA5=wA5*invA;

    const float wB0 = expf(-bD0);
    const float wB1 = (m & 0x0200) ? expf(-bD1) : 0.0f;
    const float wB2 = (m & 0x0400) ? expf(-bD2) : 0.0f;
    const float wB3 = (m & 0x0800) ? expf(-bD3) : 0.0f;
    const float wB4 = (m & 0x1000) ? expf(-bD4) : 0.0f;
    const float wB5 = (m & 0x2000) ? expf(-bD5) : 0.0f;
    const float invB = 1.0f / (wB0+wB1+wB2+wB3+wB4+wB5);
    const float nB0=wB0*invB, nB1=wB1*invB, nB2=wB2*invB,
                nB3=wB3*invB, nB4=wB4*invB, nB5=wB5*invB;

    if (h == 0) out_dist[pA] = nA0*aD0 + nA1*aD1 + nA2*aD2 + nA3*aD3 + nA4*aD4 + nA5*aD5;
    if (h == 8) out_dist[pB] = nB0*bD0 + nB1*bD1 + nB2*bD2 + nB3*bD3 + nB4*bD4 + nB5*bD5;

    // ---- transform epilogue: lane h owns element h -> coalesced 64B rows ----
    float accA = nA0 * vtf[aI0*16 + h];
    accA = fmaf(nA1, vtf[aI1*16 + h], accA);
    accA = fmaf(nA2, vtf[aI2*16 + h], accA);
    accA = fmaf(nA3, vtf[aI3*16 + h], accA);
    accA = fmaf(nA4, vtf[aI4*16 + h], accA);
    accA = fmaf(nA5, vtf[aI5*16 + h], accA);
    out_tf[pA*16 + h] = accA;

    float accB = nB0 * vtf[bI0*16 + h];
    accB = fmaf(nB1, vtf[bI1*16 + h], accB);
    accB = fmaf(nB2, vtf[bI2*16 + h], accB);
    accB = fmaf(nB3, vtf[bI3*16 + h], accB);
    accB = fmaf(nB4, vtf[bI4*16 + h], accB);
    accB = fmaf(nB5, vtf[bI5*16 + h], accB);
    out_tf[pB*16 + h] = accB;
}

extern "C" void kernel_launch(void* const* d_in, const int* in_sizes, int n_in,
                              void* d_out, int out_size, void* d_ws, size_t ws_size,
                              hipStream_t stream) {
    const float* lbs = (const float*)d_in[0];   // [10475][55]
    const float* vtf = (const float*)d_in[1];   // [10475][4][4]
    const float* pts = (const float*)d_in[2];   // [32768][3]
    const float* tpl = (const float*)d_in[3];   // [10475][3]
    float* out = (float*)d_out;
    scarf_knn_lbs<<<NPTS / PPB, BLOCK, 0, stream>>>(lbs, vtf, pts, tpl, out, out + NPTS);
}

// Round 5
// 217.433 us; speedup vs baseline: 1.3943x; 1.2119x over previous
//
#include <hip/hip_runtime.h>
#include <math.h>

// SCARF KNN+LBS-blend kernel.  B=1, N=32768, V=10475, K=6, J=55.
// out = [ xyz_dist (N floats) | xyz_transform (N*16 floats) ]
//
// NUMERICS (verified passing rounds 3-4): replicate the np reference's f32
// rounding exactly for the KNN ordering:
//   p2 = (px^2 + py^2) + pz^2            (no fma)
//   t2 = (tx^2 + ty^2) + tz^2            (no fma)
//   cross = fma(pz,tz, fma(py,ty, px*tx))  (ascending-k fma chain)
//   d2 = max((p2 + t2) - 2*cross, 0)
// DOUBLED template coords in LDS make the fma chain produce exactly 2*cross
// (powers of 2 commute with f32 rounding). Contraction off globally.
//
// ALGORITHM (round 5): two-pass threshold selection to kill the per-eval
// sorted-insert cost (round 4 was ~61 VALU instr/eval, VALUBusy 95%):
//   pass 1: per-lane top-1 (3 instr/eval) -> merge 16 lane-minima ->
//           T = 6th smallest (>= true v6 since at most 5 values < v6
//           can be lane minima).
//   pass 2: rescan, gate dd <= T (rarely taken wave-wide), survivors get
//           the full lexicographic insert; final butterfly merge.
#pragma clang fp contract(off)

#define NPTS  32768
#define NV    10475
#define JW    55
#define TILE  2048        // float4 -> 32 KB LDS
#define SPLIT 16          // lanes cooperating per point
#define BLOCK 256
#define PPB   32          // 2 points per thread-group pair -> grid 1024
#define FINF  3.4e38f

// lexicographic (dist, idx) insert (jax top_k tie rule: lower idx wins on ties)
#define LTL(dd, vv, D, I) ((dd) < (D) || ((dd) == (D) && (vv) < (I)))
#define INSL6(dd, vv, D0,I0,D1,I1,D2,I2,D3,I3,D4,I4,D5,I5) \
  if (LTL(dd, vv, D5, I5)) { \
    if (LTL(dd, vv, D4, I4)) { D5=D4; I5=I4; \
      if (LTL(dd, vv, D3, I3)) { D4=D3; I4=I3; \
        if (LTL(dd, vv, D2, I2)) { D3=D2; I3=I2; \
          if (LTL(dd, vv, D1, I1)) { D2=D1; I2=I1; \
            if (LTL(dd, vv, D0, I0)) { D1=D0; I1=I0; D0=(dd); I0=(vv); } \
            else { D1=(dd); I1=(vv); } \
          } else { D2=(dd); I2=(vv); } \
        } else { D3=(dd); I3=(vv); } \
      } else { D4=(dd); I4=(vv); } \
    } else { D5=(dd); I5=(vv); } \
  }

// butterfly step: snapshot partner's 6 FIRST (partner mutates in lockstep), then insert
#define MERGE6(S, D0,I0,D1,I1,D2,I2,D3,I3,D4,I4,D5,I5) { \
    float m0=__shfl_xor(D0,S), m1=__shfl_xor(D1,S), m2=__shfl_xor(D2,S), \
          m3=__shfl_xor(D3,S), m4=__shfl_xor(D4,S), m5=__shfl_xor(D5,S); \
    int   j0=__shfl_xor(I0,S), j1=__shfl_xor(I1,S), j2=__shfl_xor(I2,S), \
          j3=__shfl_xor(I3,S), j4=__shfl_xor(I4,S), j5=__shfl_xor(I5,S); \
    INSL6(m0,j0, D0,I0,D1,I1,D2,I2,D3,I3,D4,I4,D5,I5); \
    INSL6(m1,j1, D0,I0,D1,I1,D2,I2,D3,I3,D4,I4,D5,I5); \
    INSL6(m2,j2, D0,I0,D1,I1,D2,I2,D3,I3,D4,I4,D5,I5); \
    INSL6(m3,j3, D0,I0,D1,I1,D2,I2,D3,I3,D4,I4,D5,I5); \
    INSL6(m4,j4, D0,I0,D1,I1,D2,I2,D3,I3,D4,I4,D5,I5); \
    INSL6(m5,j5, D0,I0,D1,I1,D2,I2,D3,I3,D4,I4,D5,I5); }

__global__ __launch_bounds__(BLOCK, 4)
void scarf_knn_lbs(const float* __restrict__ lbs,   // [NV][JW]
                   const float* __restrict__ vtf,   // [NV][16]
                   const float* __restrict__ pts,   // [NPTS][3]
                   const float* __restrict__ tpl,   // [NV][3]
                   float* __restrict__ out_dist,    // [NPTS]
                   float* __restrict__ out_tf)      // [NPTS][16]
{
    __shared__ float4 s_t[TILE];

    const int tid = threadIdx.x;
    const int h   = tid & (SPLIT - 1);       // lane within point-group
    const int grp = tid >> 4;                // 0..15 group in block
    const int pA  = blockIdx.x * PPB + grp * 2;
    const int pB  = pA + 1;

    const float pxA = pts[pA*3+0], pyA = pts[pA*3+1], pzA = pts[pA*3+2];
    const float pxB = pts[pB*3+0], pyB = pts[pB*3+1], pzB = pts[pB*3+2];
    const float p2A = (pxA*pxA + pyA*pyA) + pzA*pzA;
    const float p2B = (pxB*pxB + pyB*pyB) + pzB*pzB;

    // ---- pass 1: per-lane top-1 (unclamped distance; clamp is monotone) ----
    float mA = FINF, mB = FINF;
    int  miA = -1,  miB = -1;

    for (int base = 0; base < NV; base += TILE) {
        const int tn = (NV - base < TILE) ? (NV - base) : TILE;
        __syncthreads();
        for (int i = tid; i < tn; i += BLOCK) {
            const float x = tpl[(base+i)*3+0];
            const float y = tpl[(base+i)*3+1];
            const float z = tpl[(base+i)*3+2];
            const float t2 = (x*x + y*y) + z*z;      // reference t2 rounding
            s_t[i] = make_float4(x+x, y+y, z+z, t2); // doubled coords (exact)
        }
        __syncthreads();
        #pragma unroll 4
        for (int i = h; i < tn; i += SPLIT) {
            const float4 t = s_t[i];
            const int vv = base + i;
            const float crA = fmaf(pzA, t.z, fmaf(pyA, t.y, pxA * t.x)); // == 2*cross
            const float dA  = (p2A + t.w) - crA;
            const bool  cA  = dA < mA;
            mA  = cA ? dA : mA;  miA = cA ? vv : miA;
            const float crB = fmaf(pzB, t.z, fmaf(pyB, t.y, pxB * t.x));
            const float dB  = (p2B + t.w) - crB;
            const bool  cB  = dB < mB;
            mB  = cB ? dB : mB;  miB = cB ? vv : miB;
        }
        __syncthreads();
    }

    // ---- threshold: 6th smallest of the 16 lane minima (clamped values) ----
    float aD0=fmaxf(mA,0.0f), aD1=FINF, aD2=FINF, aD3=FINF, aD4=FINF, aD5=FINF;
    int   aI0=miA, aI1=-1, aI2=-1, aI3=-1, aI4=-1, aI5=-1;
    MERGE6(1, aD0,aI0,aD1,aI1,aD2,aI2,aD3,aI3,aD4,aI4,aD5,aI5);
    MERGE6(2, aD0,aI0,aD1,aI1,aD2,aI2,aD3,aI3,aD4,aI4,aD5,aI5);
    MERGE6(4, aD0,aI0,aD1,aI1,aD2,aI2,aD3,aI3,aD4,aI4,aD5,aI5);
    MERGE6(8, aD0,aI0,aD1,aI1,aD2,aI2,aD3,aI3,aD4,aI4,aD5,aI5);
    const float TA = aD5;

    float bD0=fmaxf(mB,0.0f), bD1=FINF, bD2=FINF, bD3=FINF, bD4=FINF, bD5=FINF;
    int   bI0=miB, bI1=-1, bI2=-1, bI3=-1, bI4=-1, bI5=-1;
    MERGE6(1, bD0,bI0,bD1,bI1,bD2,bI2,bD3,bI3,bD4,bI4,bD5,bI5);
    MERGE6(2, bD0,bI0,bD1,bI1,bD2,bI2,bD3,bI3,bD4,bI4,bD5,bI5);
    MERGE6(4, bD0,bI0,bD1,bI1,bD2,bI2,bD3,bI3,bD4,bI4,bD5,bI5);
    MERGE6(8, bD0,bI0,bD1,bI1,bD2,bI2,bD3,bI3,bD4,bI4,bD5,bI5);
    const float TB = bD5;

    // ---- pass 2: rescan with threshold gate; survivors -> lexicographic list ----
    aD0=FINF; aD1=FINF; aD2=FINF; aD3=FINF; aD4=FINF; aD5=FINF;
    aI0=-1; aI1=-1; aI2=-1; aI3=-1; aI4=-1; aI5=-1;
    bD0=FINF; bD1=FINF; bD2=FINF; bD3=FINF; bD4=FINF; bD5=FINF;
    bI0=-1; bI1=-1; bI2=-1; bI3=-1; bI4=-1; bI5=-1;

    for (int base = 0; base < NV; base += TILE) {
        const int tn = (NV - base < TILE) ? (NV - base) : TILE;
        __syncthreads();
        for (int i = tid; i < tn; i += BLOCK) {
            const float x = tpl[(base+i)*3+0];
            const float y = tpl[(base+i)*3+1];
            const float z = tpl[(base+i)*3+2];
            const float t2 = (x*x + y*y) + z*z;
            s_t[i] = make_float4(x+x, y+y, z+z, t2);
        }
        __syncthreads();
        #pragma unroll 4
        for (int i = h; i < tn; i += SPLIT) {
            const float4 t = s_t[i];
            const int vv = base + i;
            const float crA = fmaf(pzA, t.z, fmaf(pyA, t.y, pxA * t.x));
            const float dA  = (p2A + t.w) - crA;
            if (dA <= TA) {   // rare wave-wide
                const float ddA = fmaxf(dA, 0.0f);
                INSL6(ddA, vv, aD0,aI0,aD1,aI1,aD2,aI2,aD3,aI3,aD4,aI4,aD5,aI5);
            }
            const float crB = fmaf(pzB, t.z, fmaf(pyB, t.y, pxB * t.x));
            const float dB  = (p2B + t.w) - crB;
            if (dB <= TB) {
                const float ddB = fmaxf(dB, 0.0f);
                INSL6(ddB, vv, bD0,bI0,bD1,bI1,bD2,bI2,bD3,bI3,bD4,bI4,bD5,bI5);
            }
        }
        __syncthreads();
    }

    // ---- final butterfly merge: every lane ends with the exact global top-6 ----
    MERGE6(1, aD0,aI0,aD1,aI1,aD2,aI2,aD3,aI3,aD4,aI4,aD5,aI5);
    MERGE6(2, aD0,aI0,aD1,aI1,aD2,aI2,aD3,aI3,aD4,aI4,aD5,aI5);
    MERGE6(4, aD0,aI0,aD1,aI1,aD2,aI2,aD3,aI3,aD4,aI4,aD5,aI5);
    MERGE6(8, aD0,aI0,aD1,aI1,aD2,aI2,aD3,aI3,aD4,aI4,aD5,aI5);
    MERGE6(1, bD0,bI0,bD1,bI1,bD2,bI2,bD3,bI3,bD4,bI4,bD5,bI5);
    MERGE6(2, bD0,bI0,bD1,bI1,bD2,bI2,bD3,bI3,bD4,bI4,bD5,bI5);
    MERGE6(4, bD0,bI0,bD1,bI1,bD2,bI2,bD3,bI3,bD4,bI4,bD5,bI5);
    MERGE6(8, bD0,bI0,bD1,bI1,bD2,bI2,bD3,bI3,bD4,bI4,bD5,bI5);

    // ---- confidence gating (verbatim from passing round 4) ----
    int rowRef, rowK, bit; bool valid;
    if (h < 8) {
        rowRef = aI0; valid = (h < 5); bit = 2 << h;
        rowK = (h==0)?aI1:(h==1)?aI2:(h==2)?aI3:(h==3)?aI4:(h==4)?aI5:aI0;
    } else {
        rowRef = bI0; valid = (h < 13); bit = 0x200 << (h - 8);
        rowK = (h==8)?bI1:(h==9)?bI2:(h==10)?bI3:(h==11)?bI4:(h==12)?bI5:bI0;
    }
    const float* ra = lbs + (long)rowK  * JW;
    const float* rb = lbs + (long)rowRef * JW;
    float s = 0.0f;
    for (int j = 0; j < JW; ++j) s += fabsf(ra[j] - rb[j]);
    int m = (valid && (expf(-s / 0.02f) > 0.9f)) ? bit : 0;
    m |= __shfl_xor(m, 1); m |= __shfl_xor(m, 2);
    m |= __shfl_xor(m, 4); m |= __shfl_xor(m, 8);

    const float wA0 = expf(-aD0);
    const float wA1 = (m & 0x002) ? expf(-aD1) : 0.0f;
    const float wA2 = (m & 0x004) ? expf(-aD2) : 0.0f;
    const float wA3 = (m & 0x008) ? expf(-aD3) : 0.0f;
    const float wA4 = (m & 0x010) ? expf(-aD4) : 0.0f;
    const float wA5 = (m & 0x020) ? expf(-aD5) : 0.0f;
    const float invA = 1.0f / (wA0+wA1+wA2+wA3+wA4+wA5);
    const float nA0=wA0*invA, nA1=wA1*invA, nA2=wA2*invA,
                nA3=wA3*invA, nA4=wA4*invA, nA5=wA5*invA;

    const float wB0 = expf(-bD0);
    const float wB1 = (m & 0x0200) ? expf(-bD1) : 0.0f;
    const float wB2 = (m & 0x0400) ? expf(-bD2) : 0.0f;
    const float wB3 = (m & 0x0800) ? expf(-bD3) : 0.0f;
    const float wB4 = (m & 0x1000) ? expf(-bD4) : 0.0f;
    const float wB5 = (m & 0x2000) ? expf(-bD5) : 0.0f;
    const float invB = 1.0f / (wB0+wB1+wB2+wB3+wB4+wB5);
    const float nB0=wB0*invB, nB1=wB1*invB, nB2=wB2*invB,
                nB3=wB3*invB, nB4=wB4*invB, nB5=wB5*invB;

    if (h == 0) out_dist[pA] = nA0*aD0 + nA1*aD1 + nA2*aD2 + nA3*aD3 + nA4*aD4 + nA5*aD5;
    if (h == 8) out_dist[pB] = nB0*bD0 + nB1*bD1 + nB2*bD2 + nB3*bD3 + nB4*bD4 + nB5*bD5;

    // ---- transform epilogue: lane h owns element h -> coalesced 64B rows ----
    float accA = nA0 * vtf[aI0*16 + h];
    accA = fmaf(nA1, vtf[aI1*16 + h], accA);
    accA = fmaf(nA2, vtf[aI2*16 + h], accA);
    accA = fmaf(nA3, vtf[aI3*16 + h], accA);
    accA = fmaf(nA4, vtf[aI4*16 + h], accA);
    accA = fmaf(nA5, vtf[aI5*16 + h], accA);
    out_tf[pA*16 + h] = accA;

    float accB = nB0 * vtf[bI0*16 + h];
    accB = fmaf(nB1, vtf[bI1*16 + h], accB);
    accB = fmaf(nB2, vtf[bI2*16 + h], accB);
    accB = fmaf(nB3, vtf[bI3*16 + h], accB);
    accB = fmaf(nB4, vtf[bI4*16 + h], accB);
    accB = fmaf(nB5, vtf[bI5*16 + h], accB);
    out_tf[pB*16 + h] = accB;
}

extern "C" void kernel_launch(void* const* d_in, const int* in_sizes, int n_in,
                              void* d_out, int out_size, void* d_ws, size_t ws_size,
                              hipStream_t stream) {
    const float* lbs = (const float*)d_in[0];   // [10475][55]
    const float* vtf = (const float*)d_in[1];   // [10475][4][4]
    const float* pts = (const float*)d_in[2];   // [32768][3]
    const float* tpl = (const float*)d_in[3];   // [10475][3]
    float* out = (float*)d_out;
    scarf_knn_lbs<<<NPTS / PPB, BLOCK, 0, stream>>>(lbs, vtf, pts, tpl, out, out + NPTS);
}

// Round 6
// 144.905 us; speedup vs baseline: 2.0921x; 1.5005x over previous
//
#include <hip/hip_runtime.h>
#include <math.h>

// SCARF KNN+LBS-blend kernel.  B=1, N=32768, V=10475, K=6, J=55.
// out = [ xyz_dist (N floats) | xyz_transform (N*16 floats) ]
//
// NUMERICS (verified passing rounds 3-5): replicate the np reference's f32
// rounding exactly for the KNN ordering:
//   p2 = (px^2 + py^2) + pz^2            (no fma)
//   t2 = (tx^2 + ty^2) + tz^2            (no fma)
//   cross = fma(pz,tz, fma(py,ty, px*tx))  (ascending-k fma chain)
//   d2 = max((p2 + t2) - 2*cross, 0)
// DOUBLED template coords in LDS make the fma chain produce exactly 2*cross
// (powers of 2 commute with f32 rounding). Contraction off globally.
//
// ALGORITHM (round 6): two-pass threshold selection, minimized inner loops:
//   pass 1: per-lane top-1 VALUE only (v_min, no index) ->
//           T = 6th smallest of the 16 clamped lane minima (>= true v6).
//   pass 2: rescan; survivors (d <= T, ~12-20/point) pushed into per-point
//           LDS buffer via ds_add_rtn counter (cheap taken-path).
//   final:  build exact top-6 from buffer with lexicographic insert —
//           total order on (d,idx) makes buffer order irrelevant, so the
//           result is the exact jax top_k answer, deterministically.
#pragma clang fp contract(off)

#define NPTS  32768
#define NV    10475
#define JW    55
#define TILE  1024        // float4 -> 16 KB LDS
#define SPLIT 16          // lanes cooperating per point
#define BLOCK 256
#define PPB   32          // points per block -> grid 1024 (4 blocks/CU)
#define CAP   64          // survivor buffer per point (expected ~12-20)
#define FINF  3.4e38f

// lexicographic (dist, idx) insert (jax top_k tie rule: lower idx wins on ties)
#define LTL(dd, vv, D, I) ((dd) < (D) || ((dd) == (D) && (vv) < (I)))
#define INSL6(dd, vv, D0,I0,D1,I1,D2,I2,D3,I3,D4,I4,D5,I5) \
  if (LTL(dd, vv, D5, I5)) { \
    if (LTL(dd, vv, D4, I4)) { D5=D4; I5=I4; \
      if (LTL(dd, vv, D3, I3)) { D4=D3; I4=I3; \
        if (LTL(dd, vv, D2, I2)) { D3=D2; I3=I2; \
          if (LTL(dd, vv, D1, I1)) { D2=D1; I2=I1; \
            if (LTL(dd, vv, D0, I0)) { D1=D0; I1=I0; D0=(dd); I0=(vv); } \
            else { D1=(dd); I1=(vv); } \
          } else { D2=(dd); I2=(vv); } \
        } else { D3=(dd); I3=(vv); } \
      } else { D4=(dd); I4=(vv); } \
    } else { D5=(dd); I5=(vv); } \
  }

// value-only sorted-6 insert (strict <; dropping dups only loosens T upward)
#define INSV6(dd, T0,T1,T2,T3,T4,T5) \
  if ((dd) < T5) { \
    if ((dd) < T4) { T5=T4; \
      if ((dd) < T3) { T4=T3; \
        if ((dd) < T2) { T3=T2; \
          if ((dd) < T1) { T2=T1; \
            if ((dd) < T0) { T1=T0; T0=(dd); } \
            else T1=(dd); \
          } else T2=(dd); \
        } else T3=(dd); \
      } else T4=(dd); \
    } else T5=(dd); \
  }

// value-only butterfly step within 16-lane group
#define MERGEV6(S, T0,T1,T2,T3,T4,T5) { \
    float m0=__shfl_xor(T0,S), m1=__shfl_xor(T1,S), m2=__shfl_xor(T2,S), \
          m3=__shfl_xor(T3,S), m4=__shfl_xor(T4,S), m5=__shfl_xor(T5,S); \
    INSV6(m0, T0,T1,T2,T3,T4,T5); INSV6(m1, T0,T1,T2,T3,T4,T5); \
    INSV6(m2, T0,T1,T2,T3,T4,T5); INSV6(m3, T0,T1,T2,T3,T4,T5); \
    INSV6(m4, T0,T1,T2,T3,T4,T5); INSV6(m5, T0,T1,T2,T3,T4,T5); }

__global__ __launch_bounds__(BLOCK, 4)
void scarf_knn_lbs(const float* __restrict__ lbs,   // [NV][JW]
                   const float* __restrict__ vtf,   // [NV][16]
                   const float* __restrict__ pts,   // [NPTS][3]
                   const float* __restrict__ tpl,   // [NV][3]
                   float* __restrict__ out_dist,    // [NPTS]
                   float* __restrict__ out_tf)      // [NPTS][16]
{
    __shared__ float4 s_t[TILE];        // 16 KB
    __shared__ float  s_bd[PPB][CAP];   // 8 KB
    __shared__ int    s_bi[PPB][CAP];   // 8 KB
    __shared__ int    s_cnt[PPB];       // 128 B

    const int tid = threadIdx.x;
    const int h   = tid & (SPLIT - 1);       // lane within point-group
    const int grp = tid >> 4;                // 0..15 group in block
    const int lpA = grp * 2, lpB = lpA + 1;  // local point ids
    const int pA  = blockIdx.x * PPB + lpA;
    const int pB  = pA + 1;

    const float pxA = pts[pA*3+0], pyA = pts[pA*3+1], pzA = pts[pA*3+2];
    const float pxB = pts[pB*3+0], pyB = pts[pB*3+1], pzB = pts[pB*3+2];
    const float p2A = (pxA*pxA + pyA*pyA) + pzA*pzA;
    const float p2B = (pxB*pxB + pyB*pyB) + pzB*pzB;

    if (tid < PPB) s_cnt[tid] = 0;

    // ---- pass 1: per-lane min VALUE (unclamped; clamp commutes with min) ----
    float mA = FINF, mB = FINF;

    for (int base = 0; base < NV; base += TILE) {
        const int tn = (NV - base < TILE) ? (NV - base) : TILE;
        __syncthreads();
        for (int i = tid; i < tn; i += BLOCK) {
            const float x = tpl[(base+i)*3+0];
            const float y = tpl[(base+i)*3+1];
            const float z = tpl[(base+i)*3+2];
            const float t2 = (x*x + y*y) + z*z;      // reference t2 rounding
            s_t[i] = make_float4(x+x, y+y, z+z, t2); // doubled coords (exact)
        }
        __syncthreads();
        #pragma unroll 4
        for (int i = h; i < tn; i += SPLIT) {
            const float4 t = s_t[i];
            const float dA = (p2A + t.w) - fmaf(pzA, t.z, fmaf(pyA, t.y, pxA * t.x));
            mA = fminf(mA, dA);
            const float dB = (p2B + t.w) - fmaf(pzB, t.z, fmaf(pyB, t.y, pxB * t.x));
            mB = fminf(mB, dB);
        }
    }

    // ---- threshold: 6th smallest of 16 clamped lane minima ----
    float a0 = fmaxf(mA, 0.0f), a1=FINF, a2=FINF, a3=FINF, a4=FINF, a5=FINF;
    MERGEV6(1, a0,a1,a2,a3,a4,a5);
    MERGEV6(2, a0,a1,a2,a3,a4,a5);
    MERGEV6(4, a0,a1,a2,a3,a4,a5);
    MERGEV6(8, a0,a1,a2,a3,a4,a5);
    const float TA = a5;

    float b0 = fmaxf(mB, 0.0f), b1=FINF, b2=FINF, b3=FINF, b4=FINF, b5=FINF;
    MERGEV6(1, b0,b1,b2,b3,b4,b5);
    MERGEV6(2, b0,b1,b2,b3,b4,b5);
    MERGEV6(4, b0,b1,b2,b3,b4,b5);
    MERGEV6(8, b0,b1,b2,b3,b4,b5);
    const float TB = b5;

    // ---- pass 2: rescan; push survivors (unclamped d <= clamped T) ----
    for (int base = 0; base < NV; base += TILE) {
        const int tn = (NV - base < TILE) ? (NV - base) : TILE;
        __syncthreads();
        for (int i = tid; i < tn; i += BLOCK) {
            const float x = tpl[(base+i)*3+0];
            const float y = tpl[(base+i)*3+1];
            const float z = tpl[(base+i)*3+2];
            const float t2 = (x*x + y*y) + z*z;
            s_t[i] = make_float4(x+x, y+y, z+z, t2);
        }
        __syncthreads();
        #pragma unroll 4
        for (int i = h; i < tn; i += SPLIT) {
            const float4 t = s_t[i];
            const int vv = base + i;
            const float dA = (p2A + t.w) - fmaf(pzA, t.z, fmaf(pyA, t.y, pxA * t.x));
            if (dA <= TA) {
                const int k = atomicAdd(&s_cnt[lpA], 1) & (CAP - 1);
                s_bd[lpA][k] = fmaxf(dA, 0.0f);
                s_bi[lpA][k] = vv;
            }
            const float dB = (p2B + t.w) - fmaf(pzB, t.z, fmaf(pyB, t.y, pxB * t.x));
            if (dB <= TB) {
                const int k = atomicAdd(&s_cnt[lpB], 1) & (CAP - 1);
                s_bd[lpB][k] = fmaxf(dB, 0.0f);
                s_bi[lpB][k] = vv;
            }
        }
    }
    __syncthreads();

    // ---- exact top-6 from survivor buffers (order-independent total order) ----
    float aD0=FINF,aD1=FINF,aD2=FINF,aD3=FINF,aD4=FINF,aD5=FINF;
    int   aI0=-1,aI1=-1,aI2=-1,aI3=-1,aI4=-1,aI5=-1;
    const int cA = min(s_cnt[lpA], CAP);
    for (int k = 0; k < cA; ++k) {
        const float dd = s_bd[lpA][k]; const int vv = s_bi[lpA][k];
        INSL6(dd, vv, aD0,aI0,aD1,aI1,aD2,aI2,aD3,aI3,aD4,aI4,aD5,aI5);
    }
    float bD0=FINF,bD1=FINF,bD2=FINF,bD3=FINF,bD4=FINF,bD5=FINF;
    int   bI0=-1,bI1=-1,bI2=-1,bI3=-1,bI4=-1,bI5=-1;
    const int cB = min(s_cnt[lpB], CAP);
    for (int k = 0; k < cB; ++k) {
        const float dd = s_bd[lpB][k]; const int vv = s_bi[lpB][k];
        INSL6(dd, vv, bD0,bI0,bD1,bI1,bD2,bI2,bD3,bI3,bD4,bI4,bD5,bI5);
    }

    // ---- confidence gating (verbatim from passing rounds 4-5) ----
    int rowRef, rowK, bit; bool valid;
    if (h < 8) {
        rowRef = aI0; valid = (h < 5); bit = 2 << h;
        rowK = (h==0)?aI1:(h==1)?aI2:(h==2)?aI3:(h==3)?aI4:(h==4)?aI5:aI0;
    } else {
        rowRef = bI0; valid = (h < 13); bit = 0x200 << (h - 8);
        rowK = (h==8)?bI1:(h==9)?bI2:(h==10)?bI3:(h==11)?bI4:(h==12)?bI5:bI0;
    }
    const float* ra = lbs + (long)rowK  * JW;
    const float* rb = lbs + (long)rowRef * JW;
    float s = 0.0f;
    for (int j = 0; j < JW; ++j) s += fabsf(ra[j] - rb[j]);
    int m = (valid && (expf(-s / 0.02f) > 0.9f)) ? bit : 0;
    m |= __shfl_xor(m, 1); m |= __shfl_xor(m, 2);
    m |= __shfl_xor(m, 4); m |= __shfl_xor(m, 8);

    const float wA0 = expf(-aD0);
    const float wA1 = (m & 0x002) ? expf(-aD1) : 0.0f;
    const float wA2 = (m & 0x004) ? expf(-aD2) : 0.0f;
    const float wA3 = (m & 0x008) ? expf(-aD3) : 0.0f;
    const float wA4 = (m & 0x010) ? expf(-aD4) : 0.0f;
    const float wA5 = (m & 0x020) ? expf(-aD5) : 0.0f;
    const float invA = 1.0f / (wA0+wA1+wA2+wA3+wA4+wA5);
    const float nA0=wA0*invA, nA1=wA1*invA, nA2=wA2*invA,
                nA3=wA3*invA, nA4=wA4*invA, nA5=wA5*invA;

    const float wB0 = expf(-bD0);
    const float wB1 = (m & 0x0200) ? expf(-bD1) : 0.0f;
    const float wB2 = (m & 0x0400) ? expf(-bD2) : 0.0f;
    const float wB3 = (m & 0x0800) ? expf(-bD3) : 0.0f;
    const float wB4 = (m & 0x1000) ? expf(-bD4) : 0.0f;
    const float wB5 = (m & 0x2000) ? expf(-bD5) : 0.0f;
    const float invB = 1.0f / (wB0+wB1+wB2+wB3+wB4+wB5);
    const float nB0=wB0*invB, nB1=wB1*invB, nB2=wB2*invB,
                nB3=wB3*invB, nB4=wB4*invB, nB5=wB5*invB;

    if (h == 0) out_dist[pA] = nA0*aD0 + nA1*aD1 + nA2*aD2 + nA3*aD3 + nA4*aD4 + nA5*aD5;
    if (h == 8) out_dist[pB] = nB0*bD0 + nB1*bD1 + nB2*bD2 + nB3*bD3 + nB4*bD4 + nB5*bD5;

    // ---- transform epilogue: lane h owns element h -> coalesced 64B rows ----
    float accA = nA0 * vtf[aI0*16 + h];
    accA = fmaf(nA1, vtf[aI1*16 + h], accA);
    accA = fmaf(nA2, vtf[aI2*16 + h], accA);
    accA = fmaf(nA3, vtf[aI3*16 + h], accA);
    accA = fmaf(nA4, vtf[aI4*16 + h], accA);
    accA = fmaf(nA5, vtf[aI5*16 + h], accA);
    out_tf[pA*16 + h] = accA;

    float accB = nB0 * vtf[bI0*16 + h];
    accB = fmaf(nB1, vtf[bI1*16 + h], accB);
    accB = fmaf(nB2, vtf[bI2*16 + h], accB);
    accB = fmaf(nB3, vtf[bI3*16 + h], accB);
    accB = fmaf(nB4, vtf[bI4*16 + h], accB);
    accB = fmaf(nB5, vtf[bI5*16 + h], accB);
    out_tf[pB*16 + h] = accB;
}

extern "C" void kernel_launch(void* const* d_in, const int* in_sizes, int n_in,
                              void* d_out, int out_size, void* d_ws, size_t ws_size,
                              hipStream_t stream) {
    const float* lbs = (const float*)d_in[0];   // [10475][55]
    const float* vtf = (const float*)d_in[1];   // [10475][4][4]
    const float* pts = (const float*)d_in[2];   // [32768][3]
    const float* tpl = (const float*)d_in[3];   // [10475][3]
    float* out = (float*)d_out;
    scarf_knn_lbs<<<NPTS / PPB, BLOCK, 0, stream>>>(lbs, vtf, pts, tpl, out, out + NPTS);
}

// Round 7
// 136.121 us; speedup vs baseline: 2.2271x; 1.0645x over previous
//
#include <hip/hip_runtime.h>
#include <math.h>

// SCARF KNN+LBS-blend kernel.  B=1, N=32768, V=10475, K=6, J=55.
// out = [ xyz_dist (N floats) | xyz_transform (N*16 floats) ]
//
// NUMERICS (verified passing rounds 3-6): replicate the np reference's f32
// rounding exactly for the KNN ordering:
//   p2 = (px^2 + py^2) + pz^2            (no fma)
//   t2 = (tx^2 + ty^2) + tz^2            (no fma)
//   cross = fma(pz,tz, fma(py,ty, px*tx))  (ascending-k fma chain)
//   d2 = max((p2 + t2) - 2*cross, 0)
// DOUBLED template coords in LDS make the fma chain produce exactly 2*cross
// (powers of 2 commute with f32 rounding). Contraction off globally.
//
// ALGORITHM (round 7): two-pass threshold selection (round 6), rebalanced to
// 32 lanes/group x 4 points/group: one ds_read_b128 serves 4 evals (was 2),
// halving per-eval issue overhead. Same superset guarantee (T = 6th smallest
// of 32 clamped lane minima >= true v6). Survivors via LDS atomic buffer;
// exact top-6 rebuilt per point by lanes h<4 (order-independent total order
// on (d,idx) => exact jax top_k semantics, deterministic).
#pragma clang fp contract(off)

#define NPTS  32768
#define NV    10475
#define JW    55
#define TILE  1024        // float4 -> 16 KB LDS
#define SPLIT 32          // lanes cooperating per point-group
#define BLOCK 256
#define PPB   32          // 8 groups x 4 points -> grid 1024 (4 blocks/CU)
#define CAP   64          // survivor buffer per point (expected ~8-15)
#define FINF  3.4e38f

// lexicographic (dist, idx) insert (jax top_k tie rule: lower idx wins on ties)
#define LTL(dd, vv, D, I) ((dd) < (D) || ((dd) == (D) && (vv) < (I)))
#define INSL6(dd, vv, D0,I0,D1,I1,D2,I2,D3,I3,D4,I4,D5,I5) \
  if (LTL(dd, vv, D5, I5)) { \
    if (LTL(dd, vv, D4, I4)) { D5=D4; I5=I4; \
      if (LTL(dd, vv, D3, I3)) { D4=D3; I4=I3; \
        if (LTL(dd, vv, D2, I2)) { D3=D2; I3=I2; \
          if (LTL(dd, vv, D1, I1)) { D2=D1; I2=I1; \
            if (LTL(dd, vv, D0, I0)) { D1=D0; I1=I0; D0=(dd); I0=(vv); } \
            else { D1=(dd); I1=(vv); } \
          } else { D2=(dd); I2=(vv); } \
        } else { D3=(dd); I3=(vv); } \
      } else { D4=(dd); I4=(vv); } \
    } else { D5=(dd); I5=(vv); } \
  }

// value-only sorted-6 insert (strict <; dropping dups only loosens T upward)
#define INSV6(dd, T0,T1,T2,T3,T4,T5) \
  if ((dd) < T5) { \
    if ((dd) < T4) { T5=T4; \
      if ((dd) < T3) { T4=T3; \
        if ((dd) < T2) { T3=T2; \
          if ((dd) < T1) { T2=T1; \
            if ((dd) < T0) { T1=T0; T0=(dd); } \
            else T1=(dd); \
          } else T2=(dd); \
        } else T3=(dd); \
      } else T4=(dd); \
    } else T5=(dd); \
  }

// value-only butterfly step (xor distances 1..16 stay within the 32-lane group)
#define MERGEV6(S, T0,T1,T2,T3,T4,T5) { \
    float m0=__shfl_xor(T0,S), m1=__shfl_xor(T1,S), m2=__shfl_xor(T2,S), \
          m3=__shfl_xor(T3,S), m4=__shfl_xor(T4,S), m5=__shfl_xor(T5,S); \
    INSV6(m0, T0,T1,T2,T3,T4,T5); INSV6(m1, T0,T1,T2,T3,T4,T5); \
    INSV6(m2, T0,T1,T2,T3,T4,T5); INSV6(m3, T0,T1,T2,T3,T4,T5); \
    INSV6(m4, T0,T1,T2,T3,T4,T5); INSV6(m5, T0,T1,T2,T3,T4,T5); }

#define THRESH6(mm, TT) { \
    float a0=fmaxf(mm,0.0f), a1=FINF, a2=FINF, a3=FINF, a4=FINF, a5=FINF; \
    MERGEV6(1,  a0,a1,a2,a3,a4,a5); \
    MERGEV6(2,  a0,a1,a2,a3,a4,a5); \
    MERGEV6(4,  a0,a1,a2,a3,a4,a5); \
    MERGEV6(8,  a0,a1,a2,a3,a4,a5); \
    MERGEV6(16, a0,a1,a2,a3,a4,a5); \
    TT = a5; }

__global__ __launch_bounds__(BLOCK, 4)
void scarf_knn_lbs(const float* __restrict__ lbs,   // [NV][JW]
                   const float* __restrict__ vtf,   // [NV][16]
                   const float* __restrict__ pts,   // [NPTS][3]
                   const float* __restrict__ tpl,   // [NV][3]
                   float* __restrict__ out_dist,    // [NPTS]
                   float* __restrict__ out_tf)      // [NPTS][16]
{
    __shared__ float4 s_t[TILE];        // 16 KB
    __shared__ float  s_bd[PPB][CAP];   // 8 KB
    __shared__ int    s_bi[PPB][CAP];   // 8 KB
    __shared__ int    s_cnt[PPB];       // 128 B
    __shared__ float  s_td[PPB][6];     // 768 B
    __shared__ int    s_ti[PPB][6];     // 768 B

    const int tid = threadIdx.x;
    const int h   = tid & (SPLIT - 1);       // lane within group
    const int grp = tid >> 5;                // 0..7
    const int lp  = grp * 4;                 // local base point
    const int p0  = blockIdx.x * PPB + lp;

    const float px0 = pts[(p0+0)*3+0], py0 = pts[(p0+0)*3+1], pz0 = pts[(p0+0)*3+2];
    const float px1 = pts[(p0+1)*3+0], py1 = pts[(p0+1)*3+1], pz1 = pts[(p0+1)*3+2];
    const float px2 = pts[(p0+2)*3+0], py2 = pts[(p0+2)*3+1], pz2 = pts[(p0+2)*3+2];
    const float px3 = pts[(p0+3)*3+0], py3 = pts[(p0+3)*3+1], pz3 = pts[(p0+3)*3+2];
    const float q0 = (px0*px0 + py0*py0) + pz0*pz0;
    const float q1 = (px1*px1 + py1*py1) + pz1*pz1;
    const float q2 = (px2*px2 + py2*py2) + pz2*pz2;
    const float q3 = (px3*px3 + py3*py3) + pz3*pz3;

    if (tid < PPB) s_cnt[tid] = 0;

    // ---- pass 1: per-lane min VALUE for 4 points ----
    float m0 = FINF, m1 = FINF, m2 = FINF, m3 = FINF;

    for (int base = 0; base < NV; base += TILE) {
        const int tn = (NV - base < TILE) ? (NV - base) : TILE;
        __syncthreads();
        for (int i = tid; i < tn; i += BLOCK) {
            const float x = tpl[(base+i)*3+0];
            const float y = tpl[(base+i)*3+1];
            const float z = tpl[(base+i)*3+2];
            const float t2 = (x*x + y*y) + z*z;      // reference t2 rounding
            s_t[i] = make_float4(x+x, y+y, z+z, t2); // doubled coords (exact)
        }
        __syncthreads();
        #pragma unroll 4
        for (int i = h; i < tn; i += SPLIT) {
            const float4 t = s_t[i];
            const float d0 = (q0 + t.w) - fmaf(pz0, t.z, fmaf(py0, t.y, px0 * t.x));
            m0 = fminf(m0, d0);
            const float d1 = (q1 + t.w) - fmaf(pz1, t.z, fmaf(py1, t.y, px1 * t.x));
            m1 = fminf(m1, d1);
            const float d2 = (q2 + t.w) - fmaf(pz2, t.z, fmaf(py2, t.y, px2 * t.x));
            m2 = fminf(m2, d2);
            const float d3 = (q3 + t.w) - fmaf(pz3, t.z, fmaf(py3, t.y, px3 * t.x));
            m3 = fminf(m3, d3);
        }
    }

    // ---- thresholds: 6th smallest of 32 clamped lane minima, per point ----
    float T0, T1, T2, T3;
    THRESH6(m0, T0);
    THRESH6(m1, T1);
    THRESH6(m2, T2);
    THRESH6(m3, T3);

    // ---- pass 2: rescan; push survivors (unclamped d <= clamped T) ----
    for (int base = 0; base < NV; base += TILE) {
        const int tn = (NV - base < TILE) ? (NV - base) : TILE;
        __syncthreads();
        for (int i = tid; i < tn; i += BLOCK) {
            const float x = tpl[(base+i)*3+0];
            const float y = tpl[(base+i)*3+1];
            const float z = tpl[(base+i)*3+2];
            const float t2 = (x*x + y*y) + z*z;
            s_t[i] = make_float4(x+x, y+y, z+z, t2);
        }
        __syncthreads();
        #pragma unroll 4
        for (int i = h; i < tn; i += SPLIT) {
            const float4 t = s_t[i];
            const int vv = base + i;
            const float d0 = (q0 + t.w) - fmaf(pz0, t.z, fmaf(py0, t.y, px0 * t.x));
            if (d0 <= T0) {
                const int k = atomicAdd(&s_cnt[lp+0], 1) & (CAP - 1);
                s_bd[lp+0][k] = fmaxf(d0, 0.0f); s_bi[lp+0][k] = vv;
            }
            const float d1 = (q1 + t.w) - fmaf(pz1, t.z, fmaf(py1, t.y, px1 * t.x));
            if (d1 <= T1) {
                const int k = atomicAdd(&s_cnt[lp+1], 1) & (CAP - 1);
                s_bd[lp+1][k] = fmaxf(d1, 0.0f); s_bi[lp+1][k] = vv;
            }
            const float d2 = (q2 + t.w) - fmaf(pz2, t.z, fmaf(py2, t.y, px2 * t.x));
            if (d2 <= T2) {
                const int k = atomicAdd(&s_cnt[lp+2], 1) & (CAP - 1);
                s_bd[lp+2][k] = fmaxf(d2, 0.0f); s_bi[lp+2][k] = vv;
            }
            const float d3 = (q3 + t.w) - fmaf(pz3, t.z, fmaf(py3, t.y, px3 * t.x));
            if (d3 <= T3) {
                const int k = atomicAdd(&s_cnt[lp+3], 1) & (CAP - 1);
                s_bd[lp+3][k] = fmaxf(d3, 0.0f); s_bi[lp+3][k] = vv;
            }
        }
    }
    __syncthreads();

    // ---- exact top-6 per point, built by lanes h<4, published to LDS ----
    if (h < 4) {
        const int lpr = lp + h;
        float D0=FINF,D1=FINF,D2=FINF,D3=FINF,D4=FINF,D5=FINF;
        int   I0=-1,I1=-1,I2=-1,I3=-1,I4=-1,I5=-1;
        const int c = min(s_cnt[lpr], CAP);
        for (int k = 0; k < c; ++k) {
            const float dd = s_bd[lpr][k]; const int vv = s_bi[lpr][k];
            INSL6(dd, vv, D0,I0,D1,I1,D2,I2,D3,I3,D4,I4,D5,I5);
        }
        s_td[lpr][0]=D0; s_td[lpr][1]=D1; s_td[lpr][2]=D2;
        s_td[lpr][3]=D3; s_td[lpr][4]=D4; s_td[lpr][5]=D5;
        s_ti[lpr][0]=I0; s_ti[lpr][1]=I1; s_ti[lpr][2]=I2;
        s_ti[lpr][3]=I3; s_ti[lpr][4]=I4; s_ti[lpr][5]=I5;
    }
    __syncthreads();

    // ---- confidence: 20 tasks per group (4 points x k=1..5) -> ballot mask ----
    bool pred = false;
    if (h < 20) {
        const int r  = h / 5;
        const int kk = h - r * 5 + 1;      // 1..5
        const int lpr = lp + r;
        const int i0 = s_ti[lpr][0];
        const int ik = s_ti[lpr][kk];
        const float* ra = lbs + (long)ik * JW;
        const float* rb = lbs + (long)i0 * JW;
        float s = 0.0f;
        for (int j = 0; j < JW; ++j) s += fabsf(ra[j] - rb[j]);
        pred = expf(-s / 0.02f) > 0.9f;
    }
    const unsigned long long bal = __ballot(pred);
    const int q = grp & 1;                  // wave-half of this group

    // ---- outputs: lane handles (point (h>>4)+2t, elem h&15), t=0,1 ----
    #pragma unroll
    for (int t = 0; t < 2; ++t) {
        const int r   = (h >> 4) + 2 * t;
        const int e   = h & 15;
        const int lpr = lp + r;
        const int P   = p0 + r;
        const unsigned mr = (unsigned)(bal >> (q * 32 + r * 5)) & 31u;

        const float d0 = s_td[lpr][0], d1 = s_td[lpr][1], d2 = s_td[lpr][2];
        const float d3 = s_td[lpr][3], d4 = s_td[lpr][4], d5 = s_td[lpr][5];
        const int   i0 = s_ti[lpr][0], i1 = s_ti[lpr][1], i2 = s_ti[lpr][2];
        const int   i3 = s_ti[lpr][3], i4 = s_ti[lpr][4], i5 = s_ti[lpr][5];

        const float w0 = expf(-d0);
        const float w1 = (mr & 1u)  ? expf(-d1) : 0.0f;
        const float w2 = (mr & 2u)  ? expf(-d2) : 0.0f;
        const float w3 = (mr & 4u)  ? expf(-d3) : 0.0f;
        const float w4 = (mr & 8u)  ? expf(-d4) : 0.0f;
        const float w5 = (mr & 16u) ? expf(-d5) : 0.0f;
        const float inv = 1.0f / (w0 + w1 + w2 + w3 + w4 + w5);
        const float n0 = w0*inv, n1 = w1*inv, n2 = w2*inv;
        const float n3 = w3*inv, n4 = w4*inv, n5 = w5*inv;

        if (e == 0)
            out_dist[P] = n0*d0 + n1*d1 + n2*d2 + n3*d3 + n4*d4 + n5*d5;

        float acc = n0 * vtf[i0*16 + e];
        acc = fmaf(n1, vtf[i1*16 + e], acc);
        acc = fmaf(n2, vtf[i2*16 + e], acc);
        acc = fmaf(n3, vtf[i3*16 + e], acc);
        acc = fmaf(n4, vtf[i4*16 + e], acc);
        acc = fmaf(n5, vtf[i5*16 + e], acc);
        out_tf[P*16 + e] = acc;
    }
}

extern "C" void kernel_launch(void* const* d_in, const int* in_sizes, int n_in,
                              void* d_out, int out_size, void* d_ws, size_t ws_size,
                              hipStream_t stream) {
    const float* lbs = (const float*)d_in[0];   // [10475][55]
    const float* vtf = (const float*)d_in[1];   // [10475][4][4]
    const float* pts = (const float*)d_in[2];   // [32768][3]
    const float* tpl = (const float*)d_in[3];   // [10475][3]
    float* out = (float*)d_out;
    scarf_knn_lbs<<<NPTS / PPB, BLOCK, 0, stream>>>(lbs, vtf, pts, tpl, out, out + NPTS);
}